// Round 7
// baseline (137.069 us; speedup 1.0000x reference)
//
#include <hip/hip_runtime.h>
#include <math.h>

#define NP 8      // paths
#define ND 128    // D = c / P
#define NC 1024   // channels = NP*ND
#define NL 4096   // sequence length
#define NB 16     // batch
#define LN_EPS 1e-5f

#define NBLK 2048           // 8 blocks/CU x 256 CUs (full co-residency)
#define RPB 8               // rows per block: 16384 / 2048

typedef float v4f __attribute__((ext_vector_type(4)));

__device__ __forceinline__ float hsum(v4f v) { return v.x + v.y + v.z + v.w; }

// GELU via expf-only tanh approx (no erff libcall -> nothing can force a
// spill of the register-resident x data). |err| vs exact erf-GELU ~1e-3,
// attenuated by sigmoid'(<=0.25) and |x|<~5.5 -> out err ~1.4e-3 << 2.8e-2.
__device__ __forceinline__ float gelu_f(float s) {
    const float t = 0.7978845608028654f * (s + 0.044715f * s * s * s);
    const float e = expf(2.f * t);
    return 0.5f * s * (1.f + (e - 1.f) / (e + 1.f));
}

__device__ __forceinline__ void gate_math(const float* __restrict__ scross,
                                          float* __restrict__ sgate,
                                          const float* ln_g, const float* ln_b,
                                          const float* W1, const float* b1,
                                          const float* W2, const float* b2) {
    float cross[NP];
    #pragma unroll
    for (int pp = 0; pp < NP; ++pp) cross[pp] = scross[pp];
    float mu = 0.f;
    #pragma unroll
    for (int pp = 0; pp < NP; ++pp) mu += cross[pp];
    mu *= (1.f / NP);
    float var = 0.f;
    #pragma unroll
    for (int pp = 0; pp < NP; ++pp) { float dl = cross[pp] - mu; var += dl * dl; }
    var *= (1.f / NP);
    const float inv = rsqrtf(var + LN_EPS);
    float h[NP];
    #pragma unroll
    for (int pp = 0; pp < NP; ++pp)
        h[pp] = (cross[pp] - mu) * inv * ln_g[pp] + ln_b[pp];
    float h2[2 * NP];
    for (int j = 0; j < 2 * NP; ++j) {
        float s = b1[j];
        #pragma unroll
        for (int pp = 0; pp < NP; ++pp) s += h[pp] * W1[pp * (2 * NP) + j];
        h2[j] = gelu_f(s);
    }
    for (int pp = 0; pp < NP; ++pp) {
        float s = b2[pp];
        #pragma unroll
        for (int j = 0; j < 2 * NP; ++j) s += h2[j] * W2[j * NP + pp];
        sgate[pp] = 1.f / (1.f + expf(-s));
    }
}

__device__ __forceinline__ void attn_math(const float* __restrict__ sy,
                                          float* __restrict__ sattn,
                                          const float* conv1_w, const float* conv2_w,
                                          const float* combine_w, const float* combine_b,
                                          int tid) {
    #pragma unroll
    for (int k = 0; k < 4; ++k) {
        const int pos = tid + 256 * k;
        const int p = pos >> 7, d = pos & 127;
        const float* rowp = sy + p * ND;
        float c1 = 0.f;
        #pragma unroll
        for (int t = 0; t < 5; ++t) {
            int dd = d + t - 2;
            float v = (dd >= 0 && dd < ND) ? rowp[dd] : 0.f;
            c1 += conv1_w[p * 5 + t] * v;
        }
        float c2 = 0.f;
        #pragma unroll
        for (int t = 0; t < 9; ++t) {
            int dd = d + t - 4;
            float v = (dd >= 0 && dd < ND) ? rowp[dd] : 0.f;
            c2 += conv2_w[p * 9 + t] * v;
        }
        const float z = combine_w[0] * c1 + combine_w[1] * c2 + combine_b[0];
        sattn[pos] = 1.f / (1.f + expf(-z));
    }
}

// ---- named register storage for 8 rows x 4 v4f (prevents array->scratch) ----
#define DECL_ROW(r) v4f xr##r##_0, xr##r##_1, xr##r##_2, xr##r##_3;
#define LOAD_ROW(r) { \
    const v4f* rp = xb + (size_t)(r) * (NL / 4); \
    xr##r##_0 = rp[tid]; xr##r##_1 = rp[tid + 256]; \
    xr##r##_2 = rp[tid + 512]; xr##r##_3 = rp[tid + 768]; \
    float ps = hsum(xr##r##_0) + hsum(xr##r##_1) + hsum(xr##r##_2) + hsum(xr##r##_3); \
    ps += __shfl_down(ps, 32, 64); ps += __shfl_down(ps, 16, 64); \
    ps += __shfl_down(ps, 8, 64);  ps += __shfl_down(ps, 4, 64); \
    ps += __shfl_down(ps, 2, 64);  ps += __shfl_down(ps, 1, 64); \
    if ((tid & 63) == 0) sred[r][tid >> 6] = ps; }
#define STORE_ROW(r) { \
    const float s = sattn[cbase + (r)] * g; \
    v4f* op = ob + (size_t)(r) * (NL / 4); \
    __builtin_nontemporal_store(xr##r##_0 * s, &op[tid]); \
    __builtin_nontemporal_store(xr##r##_1 * s, &op[tid + 256]); \
    __builtin_nontemporal_store(xr##r##_2 * s, &op[tid + 512]); \
    __builtin_nontemporal_store(xr##r##_3 * s, &op[tid + 768]); }

// ================= Fused cooperative kernel =================
__global__ __launch_bounds__(256, 8) void fused_kernel(
    const float* __restrict__ x, float* __restrict__ y, unsigned* __restrict__ cnt,
    const float* __restrict__ conv1_w, const float* __restrict__ conv2_w,
    const float* __restrict__ combine_w, const float* __restrict__ combine_b,
    const float* __restrict__ ln_g, const float* __restrict__ ln_b,
    const float* __restrict__ W1, const float* __restrict__ b1,
    const float* __restrict__ W2, const float* __restrict__ b2,
    float* __restrict__ out)
{
    const int tid   = threadIdx.x;
    const int row0  = blockIdx.x * RPB;
    const int b     = row0 >> 10;
    const int cbase = row0 & (NC - 1);
    const int p0    = cbase >> 7;

    __shared__ float sred[RPB][4];
    __shared__ float sy[NC];
    __shared__ float sattn[NC];
    __shared__ float scross[NP];
    __shared__ float sgate[NP];

    const v4f* xb = (const v4f*)x + (size_t)row0 * (NL / 4);
    v4f* ob       = (v4f*)out    + (size_t)row0 * (NL / 4);

    DECL_ROW(0) DECL_ROW(1) DECL_ROW(2) DECL_ROW(3)
    DECL_ROW(4) DECL_ROW(5) DECL_ROW(6) DECL_ROW(7)

    // ---- Phase 1: load x into registers + pool -> y ----
    LOAD_ROW(0) LOAD_ROW(1) LOAD_ROW(2) LOAD_ROW(3)
    LOAD_ROW(4) LOAD_ROW(5) LOAD_ROW(6) LOAD_ROW(7)
    __syncthreads();
    if (tid < RPB)
        y[row0 + tid] = (sred[tid][0] + sred[tid][1] + sred[tid][2] + sred[tid][3]) * (1.f / NL);
    __threadfence();            // release y to device scope (by the storing threads)
    __syncthreads();

    // ---- inline grid barrier (no call -> no forced spill) ----
    if (tid == 0) {
        __hip_atomic_fetch_add(cnt, 1u, __ATOMIC_RELEASE, __HIP_MEMORY_SCOPE_AGENT);
        while (__hip_atomic_load(cnt, __ATOMIC_ACQUIRE, __HIP_MEMORY_SCOPE_AGENT) < (unsigned)NBLK)
            __builtin_amdgcn_s_sleep(2);
    }
    __syncthreads();

    // ---- Phase 2: attn + gate for this block's batch (redundant per block) ----
    // agent-scope loads: bypass potentially-stale non-coherent XCD L2 lines.
    #pragma unroll
    for (int k = 0; k < 4; ++k) {
        const int i = tid + 256 * k;
        sy[i] = __hip_atomic_load(&y[b * NC + i], __ATOMIC_RELAXED, __HIP_MEMORY_SCOPE_AGENT);
    }
    __syncthreads();
    attn_math(sy, sattn, conv1_w, conv2_w, combine_w, combine_b, tid);
    __syncthreads();
    if (tid < 128) {            // path = tid>>4, 16 lanes per path, 8 elems each
        const int p = tid >> 4, o = (tid & 15) * 8;
        float s = 0.f;
        #pragma unroll
        for (int j = 0; j < 8; ++j) s += sattn[p * ND + o + j];
        s += __shfl_down(s, 8, 16); s += __shfl_down(s, 4, 16);
        s += __shfl_down(s, 2, 16); s += __shfl_down(s, 1, 16);
        if ((tid & 15) == 0) scross[p] = s * (1.f / ND);
    }
    __syncthreads();
    if (tid == 0) gate_math(scross, sgate, ln_g, ln_b, W1, b1, W2, b2);
    __syncthreads();

    // ---- Phase 3: scale register-resident rows, nt-store out ----
    const float g = sgate[p0];
    STORE_ROW(0) STORE_ROW(1) STORE_ROW(2) STORE_ROW(3)
    STORE_ROW(4) STORE_ROW(5) STORE_ROW(6) STORE_ROW(7)
}

// ================= Fallback path (R4 kernels) =================
__global__ __launch_bounds__(256) void pool_kernel(const float* __restrict__ x,
                                                   float* __restrict__ y) {
    const int wid  = threadIdx.x >> 6;
    const int lane = threadIdx.x & 63;
    const int row  = blockIdx.x * 4 + wid;
    const v4f* xr = (const v4f*)(x + (size_t)row * NL);
    float s = 0.f;
    #pragma unroll
    for (int i = 0; i < 16; ++i) {
        v4f v = xr[lane + i * 64];
        s += v.x + v.y + v.z + v.w;
    }
    #pragma unroll
    for (int off = 32; off; off >>= 1) s += __shfl_down(s, off, 64);
    if (lane == 0) y[row] = s * (1.f / NL);
}

__global__ __launch_bounds__(1024) void attn_kernel(
    const float* __restrict__ y,
    const float* __restrict__ conv1_w, const float* __restrict__ conv2_w,
    const float* __restrict__ combine_w, const float* __restrict__ combine_b,
    const float* __restrict__ ln_g, const float* __restrict__ ln_b,
    const float* __restrict__ W1, const float* __restrict__ b1,
    const float* __restrict__ W2, const float* __restrict__ b2,
    float* __restrict__ scale)
{
    const int b = blockIdx.x;
    const int tid = threadIdx.x;
    const int p = tid >> 7;
    const int d = tid & 127;

    __shared__ float sy[NC];
    __shared__ float sattn[NC];
    __shared__ float sred[16];
    __shared__ float sgate[NP];

    sy[tid] = y[b * NC + tid];
    __syncthreads();

    const float* rowp = sy + p * ND;
    float c1 = 0.f;
    #pragma unroll
    for (int t = 0; t < 5; ++t) {
        int dd = d + t - 2;
        float v = (dd >= 0 && dd < ND) ? rowp[dd] : 0.f;
        c1 += conv1_w[p * 5 + t] * v;
    }
    float c2 = 0.f;
    #pragma unroll
    for (int t = 0; t < 9; ++t) {
        int dd = d + t - 4;
        float v = (dd >= 0 && dd < ND) ? rowp[dd] : 0.f;
        c2 += conv2_w[p * 9 + t] * v;
    }
    const float z = combine_w[0] * c1 + combine_w[1] * c2 + combine_b[0];
    const float a = 1.f / (1.f + expf(-z));
    sattn[tid] = a;

    float r = a;
    #pragma unroll
    for (int off = 32; off; off >>= 1) r += __shfl_down(r, off, 64);
    const int lane = tid & 63, wid = tid >> 6;
    if (lane == 0) sred[wid] = r;
    __syncthreads();

    if (tid == 0) {
        float scross[NP];
        #pragma unroll
        for (int pp = 0; pp < NP; ++pp)
            scross[pp] = (sred[2 * pp] + sred[2 * pp + 1]) * (1.f / ND);
        gate_math(scross, sgate, ln_g, ln_b, W1, b1, W2, b2);
    }
    __syncthreads();

    scale[b * NC + tid] = sattn[tid] * sgate[p];
}

__global__ __launch_bounds__(256) void scale_kernel(const float* __restrict__ x,
                                                    const float* __restrict__ scale,
                                                    float* __restrict__ out) {
    const v4f* xv = (const v4f*)x;
    v4f* ov = (v4f*)out;
    const size_t n = (size_t)NB * NC * (NL / 4);
    const size_t stride = (size_t)gridDim.x * blockDim.x;
    for (size_t i = (size_t)blockIdx.x * blockDim.x + threadIdx.x; i < n; i += stride) {
        const float s = scale[i >> 10];
        v4f v = xv[i];
        v *= s;
        __builtin_nontemporal_store(v, &ov[i]);
    }
}

extern "C" void kernel_launch(void* const* d_in, const int* in_sizes, int n_in,
                              void* d_out, int out_size, void* d_ws, size_t ws_size,
                              hipStream_t stream) {
    const float* x         = (const float*)d_in[0];
    const float* conv1_w   = (const float*)d_in[1];
    const float* conv2_w   = (const float*)d_in[2];
    const float* combine_w = (const float*)d_in[3];
    const float* combine_b = (const float*)d_in[4];
    const float* ln_g      = (const float*)d_in[5];
    const float* ln_b      = (const float*)d_in[6];
    const float* W1        = (const float*)d_in[7];
    const float* b1        = (const float*)d_in[8];
    const float* W2        = (const float*)d_in[9];
    const float* b2        = (const float*)d_in[10];
    float* out = (float*)d_out;

    float* y        = (float*)d_ws;            // [0, 64KB): pooled means
    float* scale    = y + NB * NC;             // [64KB,128KB): fallback only
    unsigned* cnt   = (unsigned*)scale;        // coop path: barrier counter (overlaps scale)

    // zero the barrier counter every launch (graph-capturable, deterministic)
    hipMemsetAsync((void*)cnt, 0, 64, stream);

    int nb = 0;
    hipOccupancyMaxActiveBlocksPerMultiprocessor(&nb, fused_kernel, 256, 0);
    if (nb >= NBLK / 256) {
        void* args[] = { (void*)&x, (void*)&y, (void*)&cnt,
                         (void*)&conv1_w, (void*)&conv2_w,
                         (void*)&combine_w, (void*)&combine_b,
                         (void*)&ln_g, (void*)&ln_b,
                         (void*)&W1, (void*)&b1, (void*)&W2, (void*)&b2,
                         (void*)&out };
        hipLaunchCooperativeKernel((const void*)fused_kernel, dim3(NBLK), dim3(256),
                                   args, 0, stream);
    } else {
        pool_kernel<<<NB * NC / 4, 256, 0, stream>>>(x, y);
        attn_kernel<<<NB, 1024, 0, stream>>>(y, conv1_w, conv2_w, combine_w, combine_b,
                                             ln_g, ln_b, W1, b1, W2, b2, scale);
        scale_kernel<<<2048, 256, 0, stream>>>(x, scale, out);
    }
}